// Round 1
// baseline (342.694 us; speedup 1.0000x reference)
//
#include <hip/hip_runtime.h>

// Complex Daubechies wavelet forward decomposition, 6 levels.
// images [8,3,1024,1024] f32 -> out [8,3,2,1024,1024] f32.
//
// Per level (h=H>>i, w=W>>i):
//   vertical complex 6-tap circular conv, stride-2, lo stacked over hi along H
//   then horizontal ditto along W. Next level consumes the low-low quadrant.
//
// One block per (image-plane bc, decimated row j): lo row j and hi row j+h/2
// share the same 6 source rows. Vertical conv -> 4 rows in LDS -> horizontal
// conv -> 8 output values per column pair. The low-low quadrant is also
// staged contiguously into d_ws (ping-pong) for the next level, since the
// circular in-place update is not safe across blocks.

#define FULL_H 1024
#define FULL_W 1024
#define BC_TOTAL 24   // B*C = 8*3

template<bool HAS_IM, bool HAS_LL>
__global__ __launch_bounds__(256)
void wavelet_level_kernel(const float* __restrict__ src,
                          const float* __restrict__ lo_pass,
                          const float* __restrict__ hi_pass,
                          float* __restrict__ dst,
                          float* __restrict__ ll_out,
                          int h, int w)
{
    const int j   = blockIdx.x;     // 0 .. h/2-1
    const int bc  = blockIdx.y;     // 0 .. BC_TOTAL-1
    const int tid = threadIdx.x;
    const int h2  = h >> 1, w2 = w >> 1;

    // scaled filters (lo = LO * 2^-0.5 etc.) — uniform scalar loads
    const float sc = 0.70710678118654752440f;
    float lor[6], loi[6], hir[6], hii[6];
#pragma unroll
    for (int t = 0; t < 6; ++t) {
        lor[t] = lo_pass[t]     * sc;
        loi[t] = lo_pass[6 + t] * sc;
        hir[t] = hi_pass[t]     * sc;
        hii[t] = hi_pass[6 + t] * sc;
    }

    __shared__ float s_lr[FULL_W];  // vertical lo, real
    __shared__ float s_li[FULL_W];  // vertical lo, imag
    __shared__ float s_hr[FULL_W];  // vertical hi, real
    __shared__ float s_hi[FULL_W];  // vertical hi, imag

    // source layout: level 0 = images [bc][h][w] (im == 0);
    // level >0 = workspace [bc][2][h][w] contiguous
    const float* srcRe = src + (size_t)bc * (HAS_IM ? 2 : 1) * h * w;
    const float* srcIm = HAS_IM ? (srcRe + (size_t)h * w) : nullptr;

    const int hm = h - 1;           // h is a power of two
    const float* rrow[6];
    const float* irow[6];
#pragma unroll
    for (int t = 0; t < 6; ++t) {
        const int y = (2 * j - 3 + t + h) & hm;   // circular pad by 3
        rrow[t] = srcRe + (size_t)y * w;
        if (HAS_IM) irow[t] = srcIm + (size_t)y * w;
    }

    // ---- phase 1: vertical complex conv for row-pair j, float4 columns ----
    for (int cv = tid; cv < (w >> 2); cv += 256) {
        float alr[4] = {0.f,0.f,0.f,0.f};
        float ali[4] = {0.f,0.f,0.f,0.f};
        float ahr[4] = {0.f,0.f,0.f,0.f};
        float ahi[4] = {0.f,0.f,0.f,0.f};
#pragma unroll
        for (int t = 0; t < 6; ++t) {
            const float4 rv = reinterpret_cast<const float4*>(rrow[t])[cv];
            const float rr[4] = {rv.x, rv.y, rv.z, rv.w};
#pragma unroll
            for (int u = 0; u < 4; ++u) {
                alr[u] = fmaf(rr[u], lor[t], alr[u]);
                ali[u] = fmaf(rr[u], loi[t], ali[u]);
                ahr[u] = fmaf(rr[u], hir[t], ahr[u]);
                ahi[u] = fmaf(rr[u], hii[t], ahi[u]);
            }
            if (HAS_IM) {
                const float4 iv = reinterpret_cast<const float4*>(irow[t])[cv];
                const float ii[4] = {iv.x, iv.y, iv.z, iv.w};
#pragma unroll
                for (int u = 0; u < 4; ++u) {
                    alr[u] = fmaf(-ii[u], loi[t], alr[u]);
                    ali[u] = fmaf( ii[u], lor[t], ali[u]);
                    ahr[u] = fmaf(-ii[u], hii[t], ahr[u]);
                    ahi[u] = fmaf( ii[u], hir[t], ahi[u]);
                }
            }
        }
        reinterpret_cast<float4*>(s_lr)[cv] = make_float4(alr[0], alr[1], alr[2], alr[3]);
        reinterpret_cast<float4*>(s_li)[cv] = make_float4(ali[0], ali[1], ali[2], ali[3]);
        reinterpret_cast<float4*>(s_hr)[cv] = make_float4(ahr[0], ahr[1], ahr[2], ahr[3]);
        reinterpret_cast<float4*>(s_hi)[cv] = make_float4(ahi[0], ahi[1], ahi[2], ahi[3]);
    }
    __syncthreads();

    // ---- phase 2: horizontal complex conv from LDS, write outputs ----
    const int wm = w - 1;
    float* dstRe = dst + (size_t)(bc * 2 + 0) * FULL_H * FULL_W;
    float* dstIm = dst + (size_t)(bc * 2 + 1) * FULL_H * FULL_W;
    float* llRe = nullptr;
    float* llIm = nullptr;
    if (HAS_LL) {
        llRe = ll_out + (size_t)bc * 2 * h2 * w2;
        llIm = llRe + (size_t)h2 * w2;
    }

    for (int q = tid; q < w2; q += 256) {
        float vlr[6], vli[6], vhr[6], vhi[6];
#pragma unroll
        for (int t = 0; t < 6; ++t) {
            const int x = (2 * q - 3 + t + w) & wm;
            vlr[t] = s_lr[x]; vli[t] = s_li[x];
            vhr[t] = s_hr[x]; vhi[t] = s_hi[x];
        }
        float c1=0.f,c2=0.f,c3=0.f,c4=0.f,c5=0.f,c6=0.f,c7=0.f,c8=0.f;
        float d1=0.f,d2=0.f,d3=0.f,d4=0.f,d5=0.f,d6=0.f,d7=0.f,d8=0.f;
#pragma unroll
        for (int t = 0; t < 6; ++t) {
            c1 = fmaf(vlr[t], lor[t], c1);
            c2 = fmaf(vli[t], loi[t], c2);
            c3 = fmaf(vlr[t], loi[t], c3);
            c4 = fmaf(vli[t], lor[t], c4);
            c5 = fmaf(vlr[t], hir[t], c5);
            c6 = fmaf(vli[t], hii[t], c6);
            c7 = fmaf(vlr[t], hii[t], c7);
            c8 = fmaf(vli[t], hir[t], c8);
            d1 = fmaf(vhr[t], lor[t], d1);
            d2 = fmaf(vhi[t], loi[t], d2);
            d3 = fmaf(vhr[t], loi[t], d3);
            d4 = fmaf(vhi[t], lor[t], d4);
            d5 = fmaf(vhr[t], hir[t], d5);
            d6 = fmaf(vhi[t], hii[t], d6);
            d7 = fmaf(vhr[t], hii[t], d7);
            d8 = fmaf(vhi[t], hir[t], d8);
        }
        const float oRe0 = c1 - c2;        // low-low (also next level's input)
        const float oIm0 = c3 + c4;
        const int   j2   = j + h2;

        dstRe[(size_t)j  * FULL_W + q]      = oRe0;
        dstRe[(size_t)j  * FULL_W + q + w2] = c5 - c6;
        dstIm[(size_t)j  * FULL_W + q]      = oIm0;
        dstIm[(size_t)j  * FULL_W + q + w2] = c7 + c8;
        dstRe[(size_t)j2 * FULL_W + q]      = d1 - d2;
        dstRe[(size_t)j2 * FULL_W + q + w2] = d5 - d6;
        dstIm[(size_t)j2 * FULL_W + q]      = d3 + d4;
        dstIm[(size_t)j2 * FULL_W + q + w2] = d7 + d8;

        if (HAS_LL) {
            llRe[(size_t)j * w2 + q] = oRe0;
            llIm[(size_t)j * w2 + q] = oIm0;
        }
    }
}

extern "C" void kernel_launch(void* const* d_in, const int* in_sizes, int n_in,
                              void* d_out, int out_size, void* d_ws, size_t ws_size,
                              hipStream_t stream)
{
    const float* images = (const float*)d_in[0];
    const float* lo     = (const float*)d_in[1];
    const float* hi     = (const float*)d_in[2];
    float* out = (float*)d_out;

    // ws ping-pong: bufA holds 512x512 LL (50.3 MB), bufB holds 256x256 LL
    // (12.6 MB); smaller levels reuse the same buffers. Needs ~63 MB of ws.
    float* bufA = (float*)d_ws;
    float* bufB = bufA + (size_t)BC_TOTAL * 2 * 512 * 512;

    const dim3 blk(256);
    wavelet_level_kernel<false, true><<<dim3(512, BC_TOTAL), blk, 0, stream>>>(
        images, lo, hi, out, bufA, 1024, 1024);
    wavelet_level_kernel<true,  true><<<dim3(256, BC_TOTAL), blk, 0, stream>>>(
        bufA,   lo, hi, out, bufB,  512,  512);
    wavelet_level_kernel<true,  true><<<dim3(128, BC_TOTAL), blk, 0, stream>>>(
        bufB,   lo, hi, out, bufA,  256,  256);
    wavelet_level_kernel<true,  true><<<dim3( 64, BC_TOTAL), blk, 0, stream>>>(
        bufA,   lo, hi, out, bufB,  128,  128);
    wavelet_level_kernel<true,  true><<<dim3( 32, BC_TOTAL), blk, 0, stream>>>(
        bufB,   lo, hi, out, bufA,   64,   64);
    wavelet_level_kernel<true, false><<<dim3( 16, BC_TOTAL), blk, 0, stream>>>(
        bufA,   lo, hi, out, nullptr, 32,   32);
}